// Round 1
// baseline (199.985 us; speedup 1.0000x reference)
//
#include <hip/hip_runtime.h>
#include <hip/hip_bf16.h>
#include <stdint.h>

// Problem constants
#define KK 4
#define BB 16
#define LL 4096
#define DD 512
#define HH 128

typedef __attribute__((ext_vector_type(8))) short bf16x8;
typedef __attribute__((ext_vector_type(4))) float f32x4;
typedef __attribute__((ext_vector_type(2))) unsigned int u32x2;
typedef __attribute__((ext_vector_type(4))) unsigned int u32x4;

__device__ __forceinline__ unsigned int pack_bf16(float lo, float hi) {
  unsigned int a = __float_as_uint(lo);
  unsigned int b = __float_as_uint(hi);
  a = (a + 0x7FFFu + ((a >> 16) & 1u)) >> 16;   // RNE f32->bf16
  b = (b + 0x7FFFu + ((b >> 16) & 1u)) >> 16;
  return a | (b << 16);
}

__device__ __forceinline__ float bf2f(unsigned short u) {
  return __uint_as_float(((unsigned int)u) << 16);
}

__device__ __forceinline__ void load_lds16(const unsigned int* g, void* l) {
  // 16B per lane, LDS dest is wave-uniform base + lane*16 (pass uniform base).
  __builtin_amdgcn_global_load_lds(
      (const __attribute__((address_space(1))) unsigned int*)g,
      (__attribute__((address_space(3))) unsigned int*)l, 16, 0, 0);
}

// ---------------- kernel 0a: q_bias = W_q @ vq + ln_b ----------------
__global__ void qbias_kernel(const float* __restrict__ ln_w,
                             const float* __restrict__ ln_b,
                             const float* __restrict__ vq,
                             float* __restrict__ qb) {
  int h = threadIdx.x;
  if (h < HH) {
    float acc = ln_b[h];
    const float* wq = ln_w + (size_t)h * (DD + HH) + DD;
    for (int j = 0; j < HH; ++j) acc = fmaf(wq[j], vq[j], acc);
    qb[h] = acc;
  }
}

// ---------------- kernel 0b: W_h -> fragment-ordered bf16 ----------------
// Chunk gid = (ks*8 + nt)*64 + lane holds 8 bf16:
//   W[nt*16 + (lane&15)][ks*32 + (lane>>4)*8 + 0..7]
__global__ void wf_kernel(const float* __restrict__ ln_w,
                          unsigned int* __restrict__ wf) {
  int gid = blockIdx.x * 256 + threadIdx.x;   // 0..8191
  int ks = gid >> 9;
  int nt = (gid >> 6) & 7;
  int lane = gid & 63;
  int h = nt * 16 + (lane & 15);
  int d0 = ks * 32 + (lane >> 4) * 8;
  const float* src = ln_w + (size_t)h * (DD + HH) + d0;
  u32x4 v;
  v.x = pack_bf16(src[0], src[1]);
  v.y = pack_bf16(src[2], src[3]);
  v.z = pack_bf16(src[4], src[5]);
  v.w = pack_bf16(src[6], src[7]);
  *(u32x4*)(wf + (size_t)gid * 4) = v;
}

// ---------------- main fused kernel ----------------
// Grid: 4096 blocks = (b, l-chunk of 16). Block: 256 threads (4 waves).
// LDS: A-tile [64 rows][512 bf16] swizzled (64KB) + W double-buffer (2x8KB) = 80KB.
// Wave w owns k=w (16 rows), computes z[16x128] via 16x16x32 bf16 MFMA.
__global__ __launch_bounds__(256, 2) void agg_main(
    const float* __restrict__ hs, const unsigned int* __restrict__ wf,
    const float* __restrict__ qb, const float* __restrict__ vw,
    float* __restrict__ out) {
  extern __shared__ char smem[];
  char* smemA = smem;                 // 65536 B
  char* smemW = smem + 65536;         // 2 x 8192 B
  float* s_lds = (float*)(smem + 65536);        // alias (after GEMM)
  float* a_lds = (float*)(smem + 65536 + 256);  // alias

  const int tid = threadIdx.x;
  const int lane = tid & 63;
  const int wv = tid >> 6;            // wave 0..3  (== k)

  const int blk = blockIdx.x;
  const int b = blk >> 8;             // 256 l-chunks per b
  const int l0 = (blk & 255) << 4;

  // ---- prologue: issue W slice 0,1 prefetch, then stage A (hs -> bf16 LDS) ----
#pragma unroll
  for (int sl = 0; sl < 2; ++sl) {
#pragma unroll
    for (int c = 0; c < 2; ++c) {
      int boff = (wv * 2 + c) * 1024;           // bytes within slice
      load_lds16(wf + (((sl * 8192) + boff) >> 2) + lane * 4,
                 smemW + sl * 8192 + boff);
    }
  }

#pragma unroll
  for (int k = 0; k < KK; ++k) {
    const float* src = hs + (((size_t)k * BB + b) * LL + l0) * DD;
#pragma unroll
    for (int i = 0; i < 8; ++i) {
      int e = tid * 4 + i * 1024;               // f32 element index in 16x512 chunk
      f32x4 v = *(const f32x4*)(src + e);
      int row = e >> 9;                         // local pos 0..15
      int dby = (e & 511) * 2;                  // byte offset within row
      int arow = k * 16 + row;
      u32x2 p;
      p.x = pack_bf16(v.x, v.y);
      p.y = pack_bf16(v.z, v.w);
      *(u32x2*)(smemA + arow * 1024 + (dby ^ ((row & 7) << 4))) = p;
    }
  }
  __syncthreads();

  // ---- per-lane constants ----
  float qbr[8], vwr[8];
#pragma unroll
  for (int nt = 0; nt < 8; ++nt) {
    int h = nt * 16 + (lane & 15);
    qbr[nt] = qb[h];
    vwr[nt] = vw[h];
  }

  f32x4 acc[8];
#pragma unroll
  for (int nt = 0; nt < 8; ++nt) acc[nt] = (f32x4){0.f, 0.f, 0.f, 0.f};

  const int arow_off = (wv * 16 + (lane & 15)) * 1024;
  const int aswz = (lane & 7) << 4;
  const int asub = (lane >> 4) * 16;

  // ---- K-loop: 16 steps of 32 ----
  for (int ks = 0; ks < 16; ++ks) {
    char* wbuf = smemW + (ks & 1) * 8192;
    bf16x8 af = *(const bf16x8*)(smemA + arow_off + ((ks * 64 + asub) ^ aswz));
    bf16x8 wfv[8];
#pragma unroll
    for (int nt = 0; nt < 8; ++nt)
      wfv[nt] = *(const bf16x8*)(wbuf + (nt * 64 + lane) * 16);
#pragma unroll
    for (int nt = 0; nt < 8; ++nt)
      acc[nt] = __builtin_amdgcn_mfma_f32_16x16x32_bf16(af, wfv[nt], acc[nt], 0, 0, 0);
    __syncthreads();
    if (ks < 14) {  // prefetch slice ks+2 into the buffer just consumed
#pragma unroll
      for (int c = 0; c < 2; ++c) {
        int boff = (wv * 2 + c) * 1024;
        load_lds16(wf + ((((ks + 2) * 8192) + boff) >> 2) + lane * 4,
                   wbuf + boff);
      }
    }
  }

  // ---- epilogue: s = tanh(z + qb) . vw  (per row), then softmax over k ----
  float p[4];
#pragma unroll
  for (int j = 0; j < 4; ++j) {
    float a_s = 0.f;
#pragma unroll
    for (int nt = 0; nt < 8; ++nt) {
      float z = acc[nt][j] + qbr[nt];
      z = fminf(15.f, fmaxf(-15.f, z));
      float e = __expf(-2.f * z);
      float th = (1.f - e) * __builtin_amdgcn_rcpf(1.f + e);
      a_s = fmaf(vwr[nt], th, a_s);
    }
    p[j] = a_s;
  }
#pragma unroll
  for (int m = 1; m < 16; m <<= 1) {
#pragma unroll
    for (int j = 0; j < 4; ++j) p[j] += __shfl_xor(p[j], m, 64);
  }
  if ((lane & 15) == 0) {
    int rbase = wv * 16 + (lane >> 4) * 4;
#pragma unroll
    for (int j = 0; j < 4; ++j) s_lds[rbase + j] = p[j];
  }
  __syncthreads();

  if (tid < 16) {
    float s0 = s_lds[tid], s1 = s_lds[16 + tid];
    float s2 = s_lds[32 + tid], s3 = s_lds[48 + tid];
    float m = fmaxf(fmaxf(s0, s1), fmaxf(s2, s3));
    float e0 = __expf(s0 - m), e1 = __expf(s1 - m);
    float e2 = __expf(s2 - m), e3 = __expf(s3 - m);
    float inv = 1.f / (e0 + e1 + e2 + e3);
    a_lds[tid] = e0 * inv;
    a_lds[16 + tid] = e1 * inv;
    a_lds[32 + tid] = e2 * inv;
    a_lds[48 + tid] = e3 * inv;
  }
  __syncthreads();

  // ---- weighted sum: x[pos][d] = sum_k a_k * hs_bf16[k][pos][d] ----
  {
    int pos = tid >> 4;     // 0..15
    int dc = tid & 15;      // 32 d-elems each
    float av[4];
#pragma unroll
    for (int k = 0; k < 4; ++k) av[k] = a_lds[k * 16 + pos];
    float* outp = out + ((size_t)b * LL + l0 + pos) * DD + dc * 32;
#pragma unroll
    for (int c = 0; c < 4; ++c) {
      int dby = dc * 64 + c * 16;
      float xa[8];
#pragma unroll
      for (int j = 0; j < 8; ++j) xa[j] = 0.f;
#pragma unroll
      for (int k = 0; k < 4; ++k) {
        int row = k * 16 + pos;
        bf16x8 v = *(const bf16x8*)(smemA + row * 1024 + (dby ^ ((row & 7) << 4)));
#pragma unroll
        for (int j = 0; j < 8; ++j)
          xa[j] = fmaf(av[k], bf2f((unsigned short)v[j]), xa[j]);
      }
      f32x4 o0 = {xa[0], xa[1], xa[2], xa[3]};
      f32x4 o1 = {xa[4], xa[5], xa[6], xa[7]};
      *(f32x4*)(outp + c * 8) = o0;
      *(f32x4*)(outp + c * 8 + 4) = o1;
    }
  }
}

extern "C" void kernel_launch(void* const* d_in, const int* in_sizes, int n_in,
                              void* d_out, int out_size, void* d_ws, size_t ws_size,
                              hipStream_t stream) {
  const float* hs   = (const float*)d_in[0];
  // d_in[1] = mask (int32) — unused: softmax over k is invariant to the
  // per-(b,l) uniform -1e4 shift, so the mask cannot affect x.
  const float* ln_w = (const float*)d_in[2];
  const float* ln_b = (const float*)d_in[3];
  const float* v_w  = (const float*)d_in[4];
  const float* vq   = (const float*)d_in[5];
  float* out = (float*)d_out;

  unsigned int* wf = (unsigned int*)d_ws;          // 128KB fragment-ordered bf16 W_h
  float* qb = (float*)((char*)d_ws + 131072);      // 512B q_bias

  qbias_kernel<<<1, 128, 0, stream>>>(ln_w, ln_b, vq, qb);
  wf_kernel<<<32, 256, 0, stream>>>(ln_w, wf);
  agg_main<<<4096, 256, 81920, stream>>>(hs, wf, qb, v_w, out);
}